// Round 4
// baseline (434.608 us; speedup 1.0000x reference)
//
#include <hip/hip_runtime.h>

#define NCOEF 66           // n = 70 - 3 - 1 usable coefficients

// Uniform knots t[k] = k/69. De Boor (p=3) on uniform knots == uniform cubic
// B-spline. Per interval i (clamped to [3,65]) with s = 69*x - i:
//   a0 = (c0 + 4c1 + c2)/6,  a1 = (c2 - c0)/2,
//   a2 = (c0 - 2c1 + c2)/2,  a3 = (c3 - c0 + 3(c1 - c2))/6
//   f  = ((a3*s + a2)*s + a1)*s + a0   (3-fma Horner; exact polynomial
//   identity, so boundary clamping extrapolates identically to de Boor)
//
// LDS: FOUR contiguous copies of the 66-entry float4 table. Copy c starts at
// float4 offset 66*c -> dword base 264*c ≡ 8*c (mod 32): bank rotations
// 0/8/16/24. Lane class (lane&3) reads its own rotation -> the data-dependent
// gather's per-bank-group collision density drops ~4x vs a single table.
// (~52% of lanes broadcast tab[3], ~17% tab[65] — broadcasts are free; the
// ~31% middle lanes spread over 63 entries are the conflict source.)

__global__ __launch_bounds__(256) void spline_kernel(
    const float* __restrict__ x, const float* __restrict__ coef,
    float* __restrict__ out, int n)
{
    __shared__ float4 tab[4 * NCOEF];

    const int t = threadIdx.x;
    // Direct table build: 4 small global loads per thread (256B coef buffer,
    // L1/L2-hot after the first block) — no sc[] staging, ONE barrier only.
    if (t >= 3 && t < NCOEF) {
        float c0 = coef[t - 3], c1 = coef[t - 2], c2 = coef[t - 1], c3 = coef[t];
        const float k6 = 1.0f / 6.0f;
        float4 a = make_float4((c0 + 4.0f * c1 + c2) * k6,
                               (c2 - c0) * 0.5f,
                               (c0 - 2.0f * c1 + c2) * 0.5f,
                               (c3 - c0 + 3.0f * (c1 - c2)) * k6);
        tab[t]             = a;
        tab[NCOEF + t]     = a;
        tab[2 * NCOEF + t] = a;
        tab[3 * NCOEF + t] = a;
    }
    __syncthreads();

    const int n4     = n >> 2;
    const int stride = gridDim.x * blockDim.x;
    const int gid    = blockIdx.x * blockDim.x + t;
    const int tb     = (t & 3) * NCOEF;     // per-lane rotated table base

    const float4* __restrict__ xp = reinterpret_cast<const float4*>(x);
    float4*       __restrict__ op = reinterpret_cast<float4*>(out);

    int start = gid;

    // Fast path: this thread has (at least) 8 full float4s at grid stride.
    // With the launch config below every thread has EXACTLY 8.
    if (gid + 7 * stride < n4) {
        float4 v[8];
        #pragma unroll
        for (int k = 0; k < 8; ++k)
            v[k] = xp[gid + k * stride];

        #pragma unroll
        for (int k = 0; k < 8; ++k) {
            float4 ov;
            #pragma unroll
            for (int e = 0; e < 4; ++e) {
                float xs = (&v[k].x)[e] * 69.0f;
                float fi = floorf(xs);
                fi = fi < 3.0f ? 3.0f : (fi > 65.0f ? 65.0f : fi);  // v_med3
                float s  = xs - fi;                // exact for extrapolation
                float4 a = tab[tb + (int)fi];
                (&ov.x)[e] = fmaf(fmaf(fmaf(a.w, s, a.z), s, a.y), s, a.x);
            }
            op[gid + k * stride] = ov;
        }
        start = gid + 8 * stride;
    }

    // generic grid-stride remainder (no-op when grid exactly tiles n4)
    for (int idx = start; idx < n4; idx += stride) {
        float4 xv = xp[idx];
        float4 ov;
        #pragma unroll
        for (int e = 0; e < 4; ++e) {
            float xs = (&xv.x)[e] * 69.0f;
            float fi = floorf(xs);
            fi = fi < 3.0f ? 3.0f : (fi > 65.0f ? 65.0f : fi);
            float s  = xs - fi;
            float4 a = tab[tb + (int)fi];
            (&ov.x)[e] = fmaf(fmaf(fmaf(a.w, s, a.z), s, a.y), s, a.x);
        }
        op[idx] = ov;
    }

    // generic scalar tail (n % 4 != 0) — no-op for this problem's n
    for (int k = (n4 << 2) + gid; k < n; k += stride) {
        float xs = x[k] * 69.0f;
        float fi = floorf(xs);
        fi = fi < 3.0f ? 3.0f : (fi > 65.0f ? 65.0f : fi);
        float s  = xs - fi;
        float4 a = tab[tb + (int)fi];
        out[k] = fmaf(fmaf(fmaf(a.w, s, a.z), s, a.y), s, a.x);
    }
}

extern "C" void kernel_launch(void* const* d_in, const int* in_sizes, int n_in,
                              void* d_out, int out_size, void* d_ws, size_t ws_size,
                              hipStream_t stream) {
    const float* x    = (const float*)d_in[0];
    const float* coef = (const float*)d_in[1];
    float* out        = (float*)d_out;
    int n = in_sizes[0];

    // 8192 blocks x 256 thr = 2.097M threads; 16.77M float4 -> exactly 8
    // float4/thread, so every thread takes the 8-deep batched fast path.
    int threads = 256;
    int blocks  = 8192;
    int max_blocks = ((n >> 2) + threads - 1) / threads;
    if (max_blocks < 1) max_blocks = 1;
    if (blocks > max_blocks) blocks = max_blocks;

    spline_kernel<<<blocks, threads, 0, stream>>>(x, coef, out, n);
}